// Round 1
// baseline (36.758 us; speedup 1.0000x reference)
//
#include <hip/hip_runtime.h>

#define BATCH 16384
#define BAG   50
#define DIM   64

__global__ __launch_bounds__(256) void embag_kernel(
    const int*   __restrict__ indices,   // [BATCH, BAG]
    const float* __restrict__ weights,   // [BATCH, BAG]
    const float* __restrict__ values,    // [VOCAB, DIM]
    float*       __restrict__ out)       // [BATCH, DIM]
{
    const int gtid = blockIdx.x * blockDim.x + threadIdx.x;
    const int bag  = gtid >> 6;          // one wave (64 lanes) per bag
    const int lane = threadIdx.x & 63;   // lane == output dim (DIM==64)
    if (bag >= BATCH) return;

    // Lanes 0..BAG-1 stage this bag's indices and weights (coalesced).
    int   my_idx = 0;
    float my_w   = 0.0f;
    if (lane < BAG) {
        my_idx = indices[bag * BAG + lane];
        my_w   = weights[bag * BAG + lane];
    }

    float acc = 0.0f;
    #pragma unroll
    for (int n = 0; n < BAG; ++n) {
        // Compile-time lane index -> v_readlane -> SGPR idx/w -> scalar-base gather.
        const int   idx = __shfl(my_idx, n, 64);
        const float w   = __shfl(my_w,   n, 64);
        acc += w * values[(long long)idx * DIM + lane];   // 256B coalesced row read
    }

    out[bag * DIM + lane] = acc;
}

extern "C" void kernel_launch(void* const* d_in, const int* in_sizes, int n_in,
                              void* d_out, int out_size, void* d_ws, size_t ws_size,
                              hipStream_t stream) {
    const int*   indices = (const int*)  d_in[0];
    const float* weights = (const float*)d_in[1];
    const float* values  = (const float*)d_in[2];
    float*       out     = (float*)      d_out;

    // 1 wave per bag, 4 waves (256 threads) per block.
    const int waves_per_block = 4;
    const int blocks = (BATCH + waves_per_block - 1) / waves_per_block;
    embag_kernel<<<blocks, 256, 0, stream>>>(indices, weights, values, out);
}

// Round 2
// 36.223 us; speedup vs baseline: 1.0148x; 1.0148x over previous
//
#include <hip/hip_runtime.h>

#define BATCH 16384
#define BAG   50
#define DIM   64
#define NT    13   // ceil(BAG/4) iterations; each wave covers 4 rows/iter

__global__ __launch_bounds__(256) void embag_kernel(
    const int*   __restrict__ indices,   // [BATCH, BAG]
    const float* __restrict__ weights,   // [BATCH, BAG]
    const float* __restrict__ values,    // [VOCAB, DIM]
    float*       __restrict__ out)       // [BATCH, DIM]
{
    const int gtid = blockIdx.x * blockDim.x + threadIdx.x;
    const int bag  = gtid >> 6;            // one wave per bag
    const int lane = threadIdx.x & 63;
    const int sub  = lane >> 4;            // which of 4 rows this lane helps gather
    const int li   = lane & 15;            // 16 lanes x float4 = one 64-dim row
    if (bag >= BATCH) return;

    // Stage this wave's 13 (idx, w) pairs per lane: elements sub, sub+4, ..., sub+48.
    // Fully unrolled -> static register arrays, all loads independent.
    int   idxs[NT];
    float ws[NT];
    #pragma unroll
    for (int t = 0; t < NT; ++t) {
        const int nn = t * 4 + sub;
        const bool ok = nn < BAG;
        idxs[t] = ok ? indices[bag * BAG + nn] : 0;   // row 0 is a safe dummy
        ws[t]   = ok ? weights[bag * BAG + nn] : 0.0f;
    }

    // 13 independent 16B-per-lane gathers (4 rows per wave per load).
    float4 acc = make_float4(0.f, 0.f, 0.f, 0.f);
    #pragma unroll
    for (int t = 0; t < NT; ++t) {
        const float4 v = *reinterpret_cast<const float4*>(
            &values[(long long)idxs[t] * DIM + li * 4]);
        const float w = ws[t];
        acc.x += w * v.x;
        acc.y += w * v.y;
        acc.z += w * v.z;
        acc.w += w * v.w;
    }

    // Reduce partial sums across the 4 sub-groups (lanes ^16, ^32).
    #pragma unroll
    for (int m = 16; m <= 32; m <<= 1) {
        acc.x += __shfl_xor(acc.x, m, 64);
        acc.y += __shfl_xor(acc.y, m, 64);
        acc.z += __shfl_xor(acc.z, m, 64);
        acc.w += __shfl_xor(acc.w, m, 64);
    }

    // Lanes 0..15 hold the full 64-dim result; one float4 store each.
    if (sub == 0) {
        *reinterpret_cast<float4*>(&out[bag * DIM + li * 4]) = acc;
    }
}

extern "C" void kernel_launch(void* const* d_in, const int* in_sizes, int n_in,
                              void* d_out, int out_size, void* d_ws, size_t ws_size,
                              hipStream_t stream) {
    const int*   indices = (const int*)  d_in[0];
    const float* weights = (const float*)d_in[1];
    const float* values  = (const float*)d_in[2];
    float*       out     = (float*)      d_out;

    const int waves_per_block = 4;
    const int blocks = (BATCH + waves_per_block - 1) / waves_per_block;
    embag_kernel<<<blocks, 256, 0, stream>>>(indices, weights, values, out);
}